// Round 13
// baseline (462.669 us; speedup 1.0000x reference)
//
#include <hip/hip_runtime.h>
#include <stdint.h>

typedef __attribute__((ext_vector_type(8))) short short8;
typedef __attribute__((ext_vector_type(4))) float f32x4;
typedef __attribute__((ext_vector_type(4))) int   i32x4;
typedef __attribute__((ext_vector_type(4))) unsigned int u32x4;

#define CB 256
#define HWN 4096
#define THRW 0.75f           // window: MFMA-vs-np bound (~0.46) + 2*key-trunc (0.0625) + margin
#define KMASK 0xFFFFFC00u    // strip 10 low mantissa bits (code field)
#define MAXC 24

// RNE fp32 -> bf16-grid fp32 (final output cast)
static __device__ __forceinline__ float rbf(float x){
  unsigned int u = __builtin_bit_cast(unsigned int, x);
  u = (u + 0x7fffu + ((u >> 16) & 1u)) & 0xffff0000u;
  return __builtin_bit_cast(float, u);
}
static __device__ __forceinline__ unsigned int pk2(float a, float b){
  unsigned int ua = __builtin_bit_cast(unsigned int, a);
  unsigned int ub = __builtin_bit_cast(unsigned int, b);
  ua = (ua + 0x7fffu + ((ua >> 16) & 1u)) >> 16;
  ub = (ub + 0x7fffu + ((ub >> 16) & 1u)) & 0xffff0000u;
  return ua | ub;
}
static __device__ __forceinline__ void gld_lds16(const void* g, void* l){
  __builtin_amdgcn_global_load_lds(
      (const __attribute__((address_space(1))) unsigned int*)g,
      (__attribute__((address_space(3))) unsigned int*)l, 16, 0, 0);
}
static __device__ __forceinline__ float keyval(unsigned int k){
  return __builtin_bit_cast(float, k & KMASK);
}

// ---------------- prep: s2[n] (np-pairwise, r7-proven) + swizzled bf16 image + wT
__global__ void vq_prep(const float* __restrict__ wcb, float* __restrict__ s2g,
                        unsigned int* __restrict__ w_swz, float* __restrict__ wT){
  int n = blockIdx.x * 256 + threadIdx.x;
  const float* row = wcb + (size_t)n * CB;
  float blk[2];
  #pragma unroll
  for (int b2 = 0; b2 < 2; ++b2){
    float r[8];
    #pragma unroll
    for (int k = 0; k < 8; ++k){ float x = row[b2*128 + k]; r[k] = __fmul_rn(x, x); }
    for (int t = 1; t < 16; ++t)
      #pragma unroll
      for (int k = 0; k < 8; ++k){
        float x = row[b2*128 + t*8 + k];
        r[k] = __fadd_rn(r[k], __fmul_rn(x, x));
      }
    blk[b2] = __fadd_rn(__fadd_rn(__fadd_rn(r[0],r[1]), __fadd_rn(r[2],r[3])),
                        __fadd_rn(__fadd_rn(r[4],r[5]), __fadd_rn(r[6],r[7])));
  }
  s2g[n] = __fadd_rn(blk[0], blk[1]);
  {
    unsigned int* dst = w_swz + (size_t)n * 128;
    #pragma unroll
    for (int qp = 0; qp < 32; ++qp){
      int sg = qp ^ (n & 7);
      f32x4 va = *(const f32x4*)(row + sg*8);
      f32x4 vb = *(const f32x4*)(row + sg*8 + 4);
      u32x4 pk = { pk2(va[0],va[1]), pk2(va[2],va[3]), pk2(vb[0],vb[1]), pk2(vb[2],vb[3]) };
      *(u32x4*)(dst + qp*4) = pk;
    }
  }
  #pragma unroll 4
  for (int c = 0; c < 256; ++c)          // wT[c][n]: coalesced across threads (n)
    wT[(size_t)c * 1024 + n] = row[c];
}

// ---------------- s1: np-pairwise f32 sum of z^2 per position (r7-proven, coalesced)
__global__ void vq_s1(const float* __restrict__ ze, float* __restrict__ s1g){
  int pos = blockIdx.x * 256 + threadIdx.x;
  int b = pos >> 12, hw = pos & 4095;
  const float* zp = ze + (size_t)b * CB * HWN + hw;
  float blk[2];
  #pragma unroll
  for (int b2 = 0; b2 < 2; ++b2){
    float r[8];
    for (int t = 0; t < 16; ++t)
      #pragma unroll
      for (int k = 0; k < 8; ++k){
        float x = zp[(size_t)(b2*128 + t*8 + k) * HWN];
        float q = __fmul_rn(x, x);
        if (t == 0) r[k] = q; else r[k] = __fadd_rn(r[k], q);
      }
    blk[b2] = __fadd_rn(__fadd_rn(__fadd_rn(r[0],r[1]), __fadd_rn(r[2],r[3])),
                        __fadd_rn(__fadd_rn(r[4],r[5]), __fadd_rn(r[6],r[7])));
  }
  s1g[pos] = __fadd_rn(blk[0], blk[1]);
}

// ---------------- screen: ROLLED single-pass MFMA + top-3 keys + f64 re-rank -> selg
__global__ __launch_bounds__(256, 2)
void vq_screen(const float* __restrict__ ze, const float* __restrict__ wcb,
               const unsigned int* __restrict__ w_swz, const float* __restrict__ wT,
               const float* __restrict__ s2g, const float* __restrict__ s1g,
               int* __restrict__ selg)
{
  __shared__ __align__(16) char smem[65536];  // [0,32K) zeT | [32K,64K) B[2][16K]
  __shared__ float s2l[1024];
  __shared__ unsigned int m_key[64];
  __shared__ int   cnt[64];
  __shared__ int   ovf[64];
  __shared__ int   list[64][MAXC];
  __shared__ unsigned int kd[64];
  __shared__ int   ki[64];
  __shared__ int   fbrow[64];
  __shared__ int   nfb;

  const int tid = threadIdx.x, bid = blockIdx.x;
  const int b = bid >> 6, hw0 = (bid & 63) * 64;
  const int wid = tid >> 6, lane = tid & 63, l15 = lane & 15, lq = lane >> 4;
  const int wr = wid >> 1, wc = wid & 1;
  char* Bbuf = smem + 32768;

  // issue stage of half-chunk 0 (hides under phase A)
  {
    const char* src = (const char*)w_swz;
    #pragma unroll
    for (int j = 0; j < 4; ++j)
      gld_lds16(src + (j*256 + tid)*16, Bbuf + (j*256 + wid*64)*16);
  }

  // phase A: raw f32 z -> bf16 zeT (RNE, granule-swizzled); s2 -> LDS
  {
    const int p = tid & 63, cg = tid >> 6;
    const float* zp = ze + (size_t)b * CB * HWN + hw0 + p;
    #pragma unroll
    for (int o = 0; o < 8; ++o){
      int c0 = cg*64 + o*8;
      float v[8];
      #pragma unroll
      for (int i = 0; i < 8; ++i) v[i] = zp[(size_t)(c0 + i) * HWN];
      int g = (c0 >> 3) ^ (p & 7);
      u32x4 pk = { pk2(v[0],v[1]), pk2(v[2],v[3]), pk2(v[4],v[5]), pk2(v[6],v[7]) };
      *(u32x4*)(smem + p*512 + g*16) = pk;
    }
    #pragma unroll
    for (int k = 0; k < 4; ++k) s2l[k*256 + tid] = s2g[k*256 + tid];
  }
  if (tid < 64){ m_key[tid] = 0xffffffffu; cnt[tid] = 0; ovf[tid] = 0;
                 kd[tid] = 0xffffffffu; ki[tid] = 0x7fffffff; }
  if (tid == 0) nfb = 0;
  asm volatile("s_waitcnt vmcnt(0)" ::: "memory");
  __syncthreads();

  float szr[8];
  {
    const float* s1b = s1g + (size_t)b * HWN + hw0;
    int rowbase = wr*32 + lq*4;
    #pragma unroll
    for (int m = 0; m < 2; ++m)
      #pragma unroll
      for (int r = 0; r < 4; ++r)
        szr[m*4+r] = s1b[rowbase + m*16 + r];
  }

  const int rA0 = wr*32 + l15, rA1 = rA0 + 16, rB = wc*16 + l15;

  // hoist A fragments (read LDS once; reused across all 32 chunks)
  short8 a0f[8], a1f[8];
  int boff[8];                       // it-invariant swizzled B offsets
  #pragma unroll
  for (int ks = 0; ks < 8; ++ks){
    int gk = ks*4 + lq;
    a0f[ks] = *(const short8*)(smem + rA0*512 + ((gk ^ (rA0 & 7)) << 4));
    a1f[ks] = *(const short8*)(smem + rA1*512 + ((gk ^ (rA1 & 7)) << 4));
    boff[ks] = rB*512 + ((gk ^ (rB & 7)) << 4);
  }

  unsigned int k1[8], k2[8], k3[8];
  #pragma unroll
  for (int i = 0; i < 8; ++i){ k1[i] = k2[i] = k3[i] = 0xffffffffu; }

  int cur = 0;
  #pragma unroll 1                   // KEEP ROLLED: full unroll thrashes L1I
  for (int it = 0; it < 32; ++it){
    if (it < 31){
      const char* src = (const char*)w_swz + (size_t)(it + 1) * 16384;
      char* dst = Bbuf + (cur^1)*16384;
      #pragma unroll
      for (int j = 0; j < 4; ++j)
        gld_lds16(src + (j*256 + tid)*16, dst + (j*256 + wid*64)*16);
    }
    float sw = s2l[it*32 + wc*16 + l15];
    const int c0 = it*32 + wc*16 + l15;

    const char* Bc = Bbuf + cur*16384;
    f32x4 acc0 = {0,0,0,0}, acc1 = {0,0,0,0};
    #pragma unroll
    for (int ks = 0; ks < 8; ++ks){
      short8 b0 = *(const short8*)(Bc + boff[ks]);
      acc0 = __builtin_amdgcn_mfma_f32_16x16x32_bf16(a0f[ks], b0, acc0, 0, 0, 0);
      acc1 = __builtin_amdgcn_mfma_f32_16x16x32_bf16(a1f[ks], b0, acc1, 0, 0, 0);
    }

    #pragma unroll
    for (int m = 0; m < 2; ++m)
      #pragma unroll
      for (int r = 0; r < 4; ++r){
        int i = m*4 + r;
        float e = (m == 0) ? acc0[r] : acc1[r];
        float d = __fsub_rn(__fadd_rn(szr[i], sw), 2.0f*e);   // positive (chi2 norms)
        unsigned int key = (__float_as_uint(d) & KMASK) | (unsigned int)c0;
        if (key < k1[i]){ k3[i] = k2[i]; k2[i] = k1[i]; k1[i] = key; }
        else if (key < k2[i]){ k3[i] = k2[i]; k2[i] = key; }
        else if (key < k3[i]){ k3[i] = key; }
      }

    asm volatile("s_waitcnt vmcnt(0)" ::: "memory");
    __syncthreads();
    cur ^= 1;
  }

  // ---- per-row min over 16-lane group, merge across wc-waves
  #pragma unroll
  for (int i = 0; i < 8; ++i){
    unsigned int mk = k1[i];
    #pragma unroll
    for (int off = 1; off < 16; off <<= 1)
      mk = min(mk, (unsigned int)__shfl_xor((int)mk, off, 64));
    if (l15 == 0)
      atomicMin(&m_key[wr*32 + (i>>2)*16 + lq*4 + (i&3)], mk);
  }
  __syncthreads();

  // ---- collect candidates: trunc-val <= row_trunc_min + THRW; k3 inside -> overflow
  #pragma unroll
  for (int i = 0; i < 8; ++i){
    int row = wr*32 + (i>>2)*16 + lq*4 + (i&3);
    float tv = keyval(m_key[row]) + THRW;
    if (keyval(k1[i]) <= tv){
      int s = atomicAdd(&cnt[row], 1);
      if (s < MAXC) list[row][s] = (int)(k1[i] & 1023u); else ovf[row] = 1;
    }
    if (keyval(k2[i]) <= tv){
      int s = atomicAdd(&cnt[row], 1);
      if (s < MAXC) list[row][s] = (int)(k2[i] & 1023u); else ovf[row] = 1;
    }
    if (keyval(k3[i]) <= tv) ovf[row] = 1;
  }
  __syncthreads();

  // ---- exact f64 re-rank of candidates (r7-proven), 2-phase atomic pick
  {
    const int pos = tid & 63, sq = tid >> 6;
    const int c_ = min(cnt[pos], MAXC);
    const float* zr = ze + (size_t)b * CB * HWN + hw0 + pos;
    const float s1p = s1g[(size_t)b * HWN + hw0 + pos];
    float dloc[6];
    #pragma unroll
    for (int t = 0; t < 6; ++t){
      int slot = sq + t*4;
      if (slot < c_){
        int code = list[pos][slot];
        const float* wrow = wcb + (size_t)code * CB;
        double a = 0.0;
        #pragma unroll 8
        for (int c = 0; c < 256; ++c)
          a = fma((double)zr[(size_t)c * HWN], (double)wrow[c], a);
        float e32 = (float)a;
        float d = __fsub_rn(__fadd_rn(s1p, s2l[code]), __fmul_rn(2.0f, e32));
        dloc[t] = d;
        atomicMin(&kd[pos], __float_as_uint(d));
      }
    }
    __syncthreads();
    #pragma unroll
    for (int t = 0; t < 6; ++t){
      int slot = sq + t*4;
      if (slot < c_ && __float_as_uint(dloc[t]) == kd[pos])
        atomicMin(&ki[pos], list[pos][slot]);
    }
  }
  __syncthreads();

  // ---- compact overflow rows; cooperative exact full scan (rare, ~2-4us/row)
  if (tid < 64){
    if (ovf[tid] || cnt[tid] > MAXC){
      int s = atomicAdd(&nfb, 1);
      fbrow[s] = tid;
      kd[tid] = 0xffffffffu; ki[tid] = 0x7fffffff;
    }
  }
  __syncthreads();
  #pragma unroll 1
  for (int f = 0; f < nfb; ++f){
    const int row = fbrow[f];
    const float* zr = ze + (size_t)b * CB * HWN + hw0 + row;
    const float s1p = s1g[(size_t)b * HWN + hw0 + row];
    double a0 = 0.0, a1 = 0.0, a2 = 0.0, a3 = 0.0;
    #pragma unroll 1
    for (int c = 0; c < 256; ++c){
      double zc = (double)zr[(size_t)c * HWN];              // broadcast across threads
      const float* wc4 = wT + (size_t)c * 1024 + tid;       // coalesced
      a0 = fma(zc, (double)wc4[0],   a0);
      a1 = fma(zc, (double)wc4[256], a1);
      a2 = fma(zc, (double)wc4[512], a2);
      a3 = fma(zc, (double)wc4[768], a3);
    }
    float dv[4];
    dv[0] = __fsub_rn(__fadd_rn(s1p, s2l[tid      ]), __fmul_rn(2.0f, (float)a0));
    dv[1] = __fsub_rn(__fadd_rn(s1p, s2l[tid + 256]), __fmul_rn(2.0f, (float)a1));
    dv[2] = __fsub_rn(__fadd_rn(s1p, s2l[tid + 512]), __fmul_rn(2.0f, (float)a2));
    dv[3] = __fsub_rn(__fadd_rn(s1p, s2l[tid + 768]), __fmul_rn(2.0f, (float)a3));
    #pragma unroll
    for (int j = 0; j < 4; ++j) atomicMin(&kd[row], __float_as_uint(dv[j]));
    __syncthreads();
    unsigned int kmin = kd[row];
    #pragma unroll
    for (int j = 0; j < 4; ++j)
      if (__float_as_uint(dv[j]) == kmin) atomicMin(&ki[row], tid + j*256);
    __syncthreads();
  }

  if (tid < 64) selg[(size_t)b * HWN + hw0 + tid] = ki[tid];
}

// ---------------- epilogue: streaming STE + loss; gathers via L1-resident wT row
__global__ __launch_bounds__(256)
void vq_epi(const float* __restrict__ ze, const float* __restrict__ wT,
            const int* __restrict__ selg, float* __restrict__ out,
            float* __restrict__ partial)
{
  __shared__ float red[256];
  const int tid = threadIdx.x, bid = blockIdx.x;
  const int b = bid >> 8, c = bid & 255;
  const float* zrow = ze  + ((size_t)b * CB + c) * HWN;
  float*       orow = out + ((size_t)b * CB + c) * HWN;
  const int*   srow = selg + (size_t)b * HWN;
  const float* wrow = wT + (size_t)c * 1024;     // 4 KB, L1-resident
  float lacc = 0.f;
  #pragma unroll
  for (int k = 0; k < 4; ++k){
    int base = (k*256 + tid) * 4;
    f32x4 z4 = *(const f32x4*)(zrow + base);
    i32x4 s4 = *(const i32x4*)(srow + base);
    f32x4 o4;
    #pragma unroll
    for (int e = 0; e < 4; ++e){
      float zq = wrow[s4[e]];
      float zf = z4[e];
      float st = __fadd_rn(zf, __fsub_rn(zq, zf));   // f32 STE
      o4[e] = rbf(st);                               // final bf16 cast
      float dd = __fsub_rn(zf, zq);
      lacc = __fadd_rn(lacc, __fmul_rn(dd, dd));
    }
    *(f32x4*)(orow + base) = o4;
  }
  red[tid] = lacc;
  __syncthreads();
  for (int s = 128; s > 0; s >>= 1){
    if (tid < s) red[tid] += red[tid + s];
    __syncthreads();
  }
  if (tid == 0) partial[bid] = red[0];
}

// ---------------- loss
__global__ void vq_loss(const float* __restrict__ partial, float* __restrict__ outl){
  int t = threadIdx.x;
  if (t < 16){
    float s = 0.f;
    for (int j = 0; j < 256; ++j) s += partial[t*256 + j];
    float m = __fmul_rn(s, 1.0f / 1048576.0f);
    outl[t] = rbf(__fadd_rn(m, __fmul_rn(0.25f, m)));
  }
}

extern "C" void kernel_launch(void* const* d_in, const int* in_sizes, int n_in,
                              void* d_out, int out_size, void* d_ws, size_t ws_size,
                              hipStream_t stream)
{
  const float* ze  = (const float*)d_in[0];   // z_e  [16,256,64,64] raw f32
  const float* wcb = (const float*)d_in[1];   // embed_w [1024,256] raw f32
  float* out = (float*)d_out;                 // z_q_st (bf16-grid f32) + vq_loss[16]
  float* s2g     = (float*)d_ws;              // [1024]
  float* s1g     = s2g + 1024;                // [65536]
  int*   selg    = (int*)(s1g + 65536);       // [65536]
  float* partial = (float*)(selg + 65536);    // [4096]
  unsigned int* w_swz = (unsigned int*)(partial + 4096);  // [1024*128] = 512 KB
  float* wT      = (float*)(w_swz + 131072);  // [256*1024] = 1 MB

  hipLaunchKernelGGL(vq_prep,   dim3(4),    dim3(256), 0, stream, wcb, s2g, w_swz, wT);
  hipLaunchKernelGGL(vq_s1,     dim3(256),  dim3(256), 0, stream, ze, s1g);
  hipLaunchKernelGGL(vq_screen, dim3(1024), dim3(256), 0, stream,
                     ze, wcb, w_swz, wT, s2g, s1g, selg);
  hipLaunchKernelGGL(vq_epi,    dim3(4096), dim3(256), 0, stream,
                     ze, wT, selg, out, partial);
  hipLaunchKernelGGL(vq_loss,   dim3(1),    dim3(64), 0, stream,
                     partial, out + (size_t)16 * 256 * 4096);
}

// Round 14
// 435.234 us; speedup vs baseline: 1.0630x; 1.0630x over previous
//
#include <hip/hip_runtime.h>
#include <stdint.h>

typedef __attribute__((ext_vector_type(8))) short short8;
typedef __attribute__((ext_vector_type(4))) float f32x4;
typedef __attribute__((ext_vector_type(4))) int   i32x4;
typedef __attribute__((ext_vector_type(4))) unsigned int u32x4;

#define CB 256
#define HWN 4096
#define THRW 0.75f           // window: MFMA-vs-np bound (~0.46) + 2*key-trunc (0.0625) + margin
#define KMASK 0xFFFFFC00u    // strip 10 low mantissa bits (code field)
#define GMAX 512             // block-wide candidate list capacity

// RNE fp32 -> bf16-grid fp32 (final output cast)
static __device__ __forceinline__ float rbf(float x){
  unsigned int u = __builtin_bit_cast(unsigned int, x);
  u = (u + 0x7fffu + ((u >> 16) & 1u)) & 0xffff0000u;
  return __builtin_bit_cast(float, u);
}
static __device__ __forceinline__ unsigned int pk2(float a, float b){
  unsigned int ua = __builtin_bit_cast(unsigned int, a);
  unsigned int ub = __builtin_bit_cast(unsigned int, b);
  ua = (ua + 0x7fffu + ((ua >> 16) & 1u)) >> 16;
  ub = (ub + 0x7fffu + ((ub >> 16) & 1u)) & 0xffff0000u;
  return ua | ub;
}
static __device__ __forceinline__ void gld_lds16(const void* g, void* l){
  __builtin_amdgcn_global_load_lds(
      (const __attribute__((address_space(1))) unsigned int*)g,
      (__attribute__((address_space(3))) unsigned int*)l, 16, 0, 0);
}
static __device__ __forceinline__ float keyval(unsigned int k){
  return __builtin_bit_cast(float, k & KMASK);
}

// ---------------- prep: s2[n] (np-pairwise, r7-proven) + swizzled bf16 image + wT
__global__ void vq_prep(const float* __restrict__ wcb, float* __restrict__ s2g,
                        unsigned int* __restrict__ w_swz, float* __restrict__ wT){
  int n = blockIdx.x * 256 + threadIdx.x;
  const float* row = wcb + (size_t)n * CB;
  float blk[2];
  #pragma unroll
  for (int b2 = 0; b2 < 2; ++b2){
    float r[8];
    #pragma unroll
    for (int k = 0; k < 8; ++k){ float x = row[b2*128 + k]; r[k] = __fmul_rn(x, x); }
    for (int t = 1; t < 16; ++t)
      #pragma unroll
      for (int k = 0; k < 8; ++k){
        float x = row[b2*128 + t*8 + k];
        r[k] = __fadd_rn(r[k], __fmul_rn(x, x));
      }
    blk[b2] = __fadd_rn(__fadd_rn(__fadd_rn(r[0],r[1]), __fadd_rn(r[2],r[3])),
                        __fadd_rn(__fadd_rn(r[4],r[5]), __fadd_rn(r[6],r[7])));
  }
  s2g[n] = __fadd_rn(blk[0], blk[1]);
  {
    unsigned int* dst = w_swz + (size_t)n * 128;
    #pragma unroll
    for (int qp = 0; qp < 32; ++qp){
      int sg = qp ^ (n & 7);
      f32x4 va = *(const f32x4*)(row + sg*8);
      f32x4 vb = *(const f32x4*)(row + sg*8 + 4);
      u32x4 pk = { pk2(va[0],va[1]), pk2(va[2],va[3]), pk2(vb[0],vb[1]), pk2(vb[2],vb[3]) };
      *(u32x4*)(dst + qp*4) = pk;
    }
  }
  #pragma unroll 4
  for (int c = 0; c < 256; ++c)          // wT[c][n]: coalesced across threads (n)
    wT[(size_t)c * 1024 + n] = row[c];
}

// ---------------- s1: np-pairwise f32 sum of z^2 per position (r7-proven, coalesced)
__global__ void vq_s1(const float* __restrict__ ze, float* __restrict__ s1g){
  int pos = blockIdx.x * 256 + threadIdx.x;
  int b = pos >> 12, hw = pos & 4095;
  const float* zp = ze + (size_t)b * CB * HWN + hw;
  float blk[2];
  #pragma unroll
  for (int b2 = 0; b2 < 2; ++b2){
    float r[8];
    for (int t = 0; t < 16; ++t)
      #pragma unroll
      for (int k = 0; k < 8; ++k){
        float x = zp[(size_t)(b2*128 + t*8 + k) * HWN];
        float q = __fmul_rn(x, x);
        if (t == 0) r[k] = q; else r[k] = __fadd_rn(r[k], q);
      }
    blk[b2] = __fadd_rn(__fadd_rn(__fadd_rn(r[0],r[1]), __fadd_rn(r[2],r[3])),
                        __fadd_rn(__fadd_rn(r[4],r[5]), __fadd_rn(r[6],r[7])));
  }
  s1g[pos] = __fadd_rn(blk[0], blk[1]);
}

// ---------------- screen: MFMA pass + top-3 keys + COALESCED wave-per-candidate rerank
__global__ __launch_bounds__(256, 2)
void vq_screen(const float* __restrict__ ze, const float* __restrict__ wcb,
               const unsigned int* __restrict__ w_swz, const float* __restrict__ wT,
               const float* __restrict__ s2g, const float* __restrict__ s1g,
               int* __restrict__ selg)
{
  __shared__ __align__(16) char smem[65536];  // loop: zeT|B[2]; after: zf32[64][256]
  __shared__ float s2l[1024];
  __shared__ float s1l[64];
  __shared__ unsigned int m_key[64];
  __shared__ int   ovf[64];
  __shared__ unsigned short glist[GMAX];
  __shared__ float dex[GMAX];
  __shared__ unsigned int kd[64];
  __shared__ int   ki[64];
  __shared__ int   fbrow[64];
  __shared__ int   ncand, gov, nfb;

  const int tid = threadIdx.x, bid = blockIdx.x;
  const int b = bid >> 6, hw0 = (bid & 63) * 64;
  const int wid = tid >> 6, lane = tid & 63, l15 = lane & 15, lq = lane >> 4;
  const int wr = wid >> 1, wc = wid & 1;
  char* Bbuf = smem + 32768;

  // issue stage of half-chunk 0 (hides under phase A)
  {
    const char* src = (const char*)w_swz;
    #pragma unroll
    for (int j = 0; j < 4; ++j)
      gld_lds16(src + (j*256 + tid)*16, Bbuf + (j*256 + wid*64)*16);
  }

  // phase A: raw f32 z -> bf16 zeT (RNE, granule-swizzled); s2,s1 -> LDS
  {
    const int p = tid & 63, cg = tid >> 6;
    const float* zp = ze + (size_t)b * CB * HWN + hw0 + p;
    #pragma unroll
    for (int o = 0; o < 8; ++o){
      int c0 = cg*64 + o*8;
      float v[8];
      #pragma unroll
      for (int i = 0; i < 8; ++i) v[i] = zp[(size_t)(c0 + i) * HWN];
      int g = (c0 >> 3) ^ (p & 7);
      u32x4 pk = { pk2(v[0],v[1]), pk2(v[2],v[3]), pk2(v[4],v[5]), pk2(v[6],v[7]) };
      *(u32x4*)(smem + p*512 + g*16) = pk;
    }
    #pragma unroll
    for (int k = 0; k < 4; ++k) s2l[k*256 + tid] = s2g[k*256 + tid];
  }
  if (tid < 64){ m_key[tid] = 0xffffffffu; ovf[tid] = 0;
                 kd[tid] = 0xffffffffu; ki[tid] = 0x7fffffff;
                 s1l[tid] = s1g[(size_t)b * HWN + hw0 + tid]; }
  if (tid == 0){ ncand = 0; gov = 0; nfb = 0; }
  asm volatile("s_waitcnt vmcnt(0)" ::: "memory");
  __syncthreads();

  float szr[8];
  {
    int rowbase = wr*32 + lq*4;
    #pragma unroll
    for (int m = 0; m < 2; ++m)
      #pragma unroll
      for (int r = 0; r < 4; ++r)
        szr[m*4+r] = s1l[rowbase + m*16 + r];
  }

  const int rA0 = wr*32 + l15, rA1 = rA0 + 16, rB = wc*16 + l15;

  // hoist A fragments (read LDS once; reused across all 32 chunks)
  short8 a0f[8], a1f[8];
  int boff[8];
  #pragma unroll
  for (int ks = 0; ks < 8; ++ks){
    int gk = ks*4 + lq;
    a0f[ks] = *(const short8*)(smem + rA0*512 + ((gk ^ (rA0 & 7)) << 4));
    a1f[ks] = *(const short8*)(smem + rA1*512 + ((gk ^ (rA1 & 7)) << 4));
    boff[ks] = rB*512 + ((gk ^ (rB & 7)) << 4);
  }

  unsigned int k1[8], k2[8], k3[8];
  #pragma unroll
  for (int i = 0; i < 8; ++i){ k1[i] = k2[i] = k3[i] = 0xffffffffu; }

  int cur = 0;
  #pragma unroll 1
  for (int it = 0; it < 32; ++it){
    if (it < 31){
      const char* src = (const char*)w_swz + (size_t)(it + 1) * 16384;
      char* dst = Bbuf + (cur^1)*16384;
      #pragma unroll
      for (int j = 0; j < 4; ++j)
        gld_lds16(src + (j*256 + tid)*16, dst + (j*256 + wid*64)*16);
    }
    float sw = s2l[it*32 + wc*16 + l15];
    const int c0 = it*32 + wc*16 + l15;

    const char* Bc = Bbuf + cur*16384;
    f32x4 acc0 = {0,0,0,0}, acc1 = {0,0,0,0};
    #pragma unroll
    for (int ks = 0; ks < 8; ++ks){
      short8 b0 = *(const short8*)(Bc + boff[ks]);
      acc0 = __builtin_amdgcn_mfma_f32_16x16x32_bf16(a0f[ks], b0, acc0, 0, 0, 0);
      acc1 = __builtin_amdgcn_mfma_f32_16x16x32_bf16(a1f[ks], b0, acc1, 0, 0, 0);
    }

    #pragma unroll
    for (int m = 0; m < 2; ++m)
      #pragma unroll
      for (int r = 0; r < 4; ++r){
        int i = m*4 + r;
        float e = (m == 0) ? acc0[r] : acc1[r];
        float d = __fsub_rn(__fadd_rn(szr[i], sw), 2.0f*e);   // positive (chi2 norms)
        unsigned int key = (__float_as_uint(d) & KMASK) | (unsigned int)c0;
        if (key < k1[i]){ k3[i] = k2[i]; k2[i] = k1[i]; k1[i] = key; }
        else if (key < k2[i]){ k3[i] = k2[i]; k2[i] = key; }
        else if (key < k3[i]){ k3[i] = key; }
      }

    asm volatile("s_waitcnt vmcnt(0)" ::: "memory");
    __syncthreads();
    cur ^= 1;
  }

  // ---- per-row min of keys (16-lane shfl + LDS atomicMin)
  #pragma unroll
  for (int i = 0; i < 8; ++i){
    unsigned int mk = k1[i];
    #pragma unroll
    for (int off = 1; off < 16; off <<= 1)
      mk = min(mk, (unsigned int)__shfl_xor((int)mk, off, 64));
    if (l15 == 0)
      atomicMin(&m_key[wr*32 + (i>>2)*16 + lq*4 + (i&3)], mk);
  }

  // ---- restage raw f32 z into freed smem: zf32[p][(c+p)&255] (rotation swizzle)
  {
    const int p = tid & 63, cg = tid >> 6;
    const float* zp = ze + (size_t)b * CB * HWN + hw0 + p;
    float* zf = (float*)smem;
    #pragma unroll 8
    for (int k = 0; k < 64; ++k){
      int c = cg*64 + k;
      zf[p*256 + ((c + p) & 255)] = zp[(size_t)c * HWN];
    }
  }
  __syncthreads();   // m_key final AND zf32 complete

  // ---- collect candidates into block-wide list; k3-in-window -> row fallback
  #pragma unroll
  for (int i = 0; i < 8; ++i){
    int row = wr*32 + (i>>2)*16 + lq*4 + (i&3);
    float tv = keyval(m_key[row]) + THRW;
    if (keyval(k1[i]) <= tv){
      int gi = atomicAdd(&ncand, 1);
      if (gi < GMAX) glist[gi] = (unsigned short)((row << 10) | (int)(k1[i] & 1023u));
      else gov = 1;
    }
    if (keyval(k2[i]) <= tv){
      int gi = atomicAdd(&ncand, 1);
      if (gi < GMAX) glist[gi] = (unsigned short)((row << 10) | (int)(k2[i] & 1023u));
      else gov = 1;
    }
    if (keyval(k3[i]) <= tv) ovf[row] = 1;
  }
  __syncthreads();

  // ---- COALESCED exact f64 rerank: one candidate per wave, channels across lanes
  {
    const float* zf = (const float*)smem;
    const int nc = min(ncand, GMAX);
    for (int ci = wid; ci < nc; ci += 4){
      unsigned int ent = glist[ci];
      int pos = ent >> 10, code = ent & 1023;
      const float* wrow = wcb + (size_t)code * CB;
      double a = 0.0;
      #pragma unroll
      for (int k = 0; k < 4; ++k){
        int c = k*64 + lane;
        a = fma((double)zf[pos*256 + ((c + pos) & 255)], (double)wrow[c], a);
      }
      #pragma unroll
      for (int off = 1; off < 64; off <<= 1)
        a += __shfl_xor(a, off, 64);        // deterministic f64 tree
      float e32 = (float)a;
      float d = __fsub_rn(__fadd_rn(s1l[pos], s2l[code]), __fmul_rn(2.0f, e32));
      if (lane == 0){
        dex[ci] = d;
        atomicMin(&kd[pos], __float_as_uint(d));
      }
    }
  }
  __syncthreads();
  // tie-break: exact equal-bits -> lowest index (np first-occurrence)
  for (int ci = tid; ci < min(ncand, GMAX); ci += 256){
    unsigned int ent = glist[ci];
    int pos = ent >> 10, code = ent & 1023;
    if (__float_as_uint(dex[ci]) == kd[pos]) atomicMin(&ki[pos], code);
  }
  __syncthreads();

  // ---- fallback rows (k3-in-window / list overflow): cooperative full scan
  if (tid < 64){
    if (ovf[tid] || gov){
      int s = atomicAdd(&nfb, 1);
      fbrow[s] = tid;
      kd[tid] = 0xffffffffu; ki[tid] = 0x7fffffff;
    }
  }
  __syncthreads();
  #pragma unroll 1
  for (int f = 0; f < nfb; ++f){
    const int row = fbrow[f];
    const float* zf = (const float*)smem;
    const float s1p = s1l[row];
    double a0 = 0.0, a1 = 0.0, a2 = 0.0, a3 = 0.0;
    #pragma unroll 1
    for (int c = 0; c < 256; ++c){
      double zc = (double)zf[row*256 + ((c + row) & 255)];   // LDS broadcast
      const float* wc4 = wT + (size_t)c * 1024 + tid;        // coalesced
      a0 = fma(zc, (double)wc4[0],   a0);
      a1 = fma(zc, (double)wc4[256], a1);
      a2 = fma(zc, (double)wc4[512], a2);
      a3 = fma(zc, (double)wc4[768], a3);
    }
    float dv[4];
    dv[0] = __fsub_rn(__fadd_rn(s1p, s2l[tid      ]), __fmul_rn(2.0f, (float)a0));
    dv[1] = __fsub_rn(__fadd_rn(s1p, s2l[tid + 256]), __fmul_rn(2.0f, (float)a1));
    dv[2] = __fsub_rn(__fadd_rn(s1p, s2l[tid + 512]), __fmul_rn(2.0f, (float)a2));
    dv[3] = __fsub_rn(__fadd_rn(s1p, s2l[tid + 768]), __fmul_rn(2.0f, (float)a3));
    #pragma unroll
    for (int j = 0; j < 4; ++j) atomicMin(&kd[row], __float_as_uint(dv[j]));
    __syncthreads();
    unsigned int kmin = kd[row];
    #pragma unroll
    for (int j = 0; j < 4; ++j)
      if (__float_as_uint(dv[j]) == kmin) atomicMin(&ki[row], tid + j*256);
    __syncthreads();
  }

  if (tid < 64) selg[(size_t)b * HWN + hw0 + tid] = ki[tid];
}

// ---------------- epilogue: streaming STE + loss; gathers via L1-resident wT row
__global__ __launch_bounds__(256)
void vq_epi(const float* __restrict__ ze, const float* __restrict__ wT,
            const int* __restrict__ selg, float* __restrict__ out,
            float* __restrict__ partial)
{
  __shared__ float red[256];
  const int tid = threadIdx.x, bid = blockIdx.x;
  const int b = bid >> 8, c = bid & 255;
  const float* zrow = ze  + ((size_t)b * CB + c) * HWN;
  float*       orow = out + ((size_t)b * CB + c) * HWN;
  const int*   srow = selg + (size_t)b * HWN;
  const float* wrow = wT + (size_t)c * 1024;     // 4 KB, L1-resident
  float lacc = 0.f;
  #pragma unroll
  for (int k = 0; k < 4; ++k){
    int base = (k*256 + tid) * 4;
    f32x4 z4 = *(const f32x4*)(zrow + base);
    i32x4 s4 = *(const i32x4*)(srow + base);
    f32x4 o4;
    #pragma unroll
    for (int e = 0; e < 4; ++e){
      float zq = wrow[s4[e]];
      float zf = z4[e];
      float st = __fadd_rn(zf, __fsub_rn(zq, zf));   // f32 STE
      o4[e] = rbf(st);                               // final bf16 cast
      float dd = __fsub_rn(zf, zq);
      lacc = __fadd_rn(lacc, __fmul_rn(dd, dd));
    }
    *(f32x4*)(orow + base) = o4;
  }
  red[tid] = lacc;
  __syncthreads();
  for (int s = 128; s > 0; s >>= 1){
    if (tid < s) red[tid] += red[tid + s];
    __syncthreads();
  }
  if (tid == 0) partial[bid] = red[0];
}

// ---------------- loss
__global__ void vq_loss(const float* __restrict__ partial, float* __restrict__ outl){
  int t = threadIdx.x;
  if (t < 16){
    float s = 0.f;
    for (int j = 0; j < 256; ++j) s += partial[t*256 + j];
    float m = __fmul_rn(s, 1.0f / 1048576.0f);
    outl[t] = rbf(__fadd_rn(m, __fmul_rn(0.25f, m)));
  }
}

extern "C" void kernel_launch(void* const* d_in, const int* in_sizes, int n_in,
                              void* d_out, int out_size, void* d_ws, size_t ws_size,
                              hipStream_t stream)
{
  const float* ze  = (const float*)d_in[0];   // z_e  [16,256,64,64] raw f32
  const float* wcb = (const float*)d_in[1];   // embed_w [1024,256] raw f32
  float* out = (float*)d_out;                 // z_q_st (bf16-grid f32) + vq_loss[16]
  float* s2g     = (float*)d_ws;              // [1024]
  float* s1g     = s2g + 1024;                // [65536]
  int*   selg    = (int*)(s1g + 65536);       // [65536]
  float* partial = (float*)(selg + 65536);    // [4096]
  unsigned int* w_swz = (unsigned int*)(partial + 4096);  // [1024*128] = 512 KB
  float* wT      = (float*)(w_swz + 131072);  // [256*1024] = 1 MB

  hipLaunchKernelGGL(vq_prep,   dim3(4),    dim3(256), 0, stream, wcb, s2g, w_swz, wT);
  hipLaunchKernelGGL(vq_s1,     dim3(256),  dim3(256), 0, stream, ze, s1g);
  hipLaunchKernelGGL(vq_screen, dim3(1024), dim3(256), 0, stream,
                     ze, wcb, w_swz, wT, s2g, s1g, selg);
  hipLaunchKernelGGL(vq_epi,    dim3(4096), dim3(256), 0, stream,
                     ze, wT, selg, out, partial);
  hipLaunchKernelGGL(vq_loss,   dim3(1),    dim3(64), 0, stream,
                     partial, out + (size_t)16 * 256 * 4096);
}

// Round 15
// 415.014 us; speedup vs baseline: 1.1148x; 1.0487x over previous
//
#include <hip/hip_runtime.h>
#include <stdint.h>

typedef __attribute__((ext_vector_type(8))) short short8;
typedef __attribute__((ext_vector_type(4))) float f32x4;
typedef __attribute__((ext_vector_type(4))) int   i32x4;
typedef __attribute__((ext_vector_type(4))) unsigned int u32x4;

#define CB 256
#define HWN 4096
#define THRW 0.75f           // window: MFMA-vs-np bound (~0.46) + 2*key-trunc (0.0625) + margin
#define KMASK 0xFFFFFC00u    // strip 10 low mantissa bits (code field)
#define GMAX 320             // block-wide candidate list capacity
#define RECU32 400           // per-block record stride (u32): 4 hdr + 320 entries + 64 ovf

// RNE fp32 -> bf16-grid fp32 (final output cast)
static __device__ __forceinline__ float rbf(float x){
  unsigned int u = __builtin_bit_cast(unsigned int, x);
  u = (u + 0x7fffu + ((u >> 16) & 1u)) & 0xffff0000u;
  return __builtin_bit_cast(float, u);
}
static __device__ __forceinline__ unsigned int pk2(float a, float b){
  unsigned int ua = __builtin_bit_cast(unsigned int, a);
  unsigned int ub = __builtin_bit_cast(unsigned int, b);
  ua = (ua + 0x7fffu + ((ua >> 16) & 1u)) >> 16;
  ub = (ub + 0x7fffu + ((ub >> 16) & 1u)) & 0xffff0000u;
  return ua | ub;
}
static __device__ __forceinline__ void gld_lds16(const void* g, void* l){
  __builtin_amdgcn_global_load_lds(
      (const __attribute__((address_space(1))) unsigned int*)g,
      (__attribute__((address_space(3))) unsigned int*)l, 16, 0, 0);
}
static __device__ __forceinline__ float keyval(unsigned int k){
  return __builtin_bit_cast(float, k & KMASK);
}

// ---------------- prep: s2[n] (np-pairwise, r7-proven) + swizzled bf16 image + wT
__global__ void vq_prep(const float* __restrict__ wcb, float* __restrict__ s2g,
                        unsigned int* __restrict__ w_swz, float* __restrict__ wT){
  int n = blockIdx.x * 256 + threadIdx.x;
  const float* row = wcb + (size_t)n * CB;
  float blk[2];
  #pragma unroll
  for (int b2 = 0; b2 < 2; ++b2){
    float r[8];
    #pragma unroll
    for (int k = 0; k < 8; ++k){ float x = row[b2*128 + k]; r[k] = __fmul_rn(x, x); }
    for (int t = 1; t < 16; ++t)
      #pragma unroll
      for (int k = 0; k < 8; ++k){
        float x = row[b2*128 + t*8 + k];
        r[k] = __fadd_rn(r[k], __fmul_rn(x, x));
      }
    blk[b2] = __fadd_rn(__fadd_rn(__fadd_rn(r[0],r[1]), __fadd_rn(r[2],r[3])),
                        __fadd_rn(__fadd_rn(r[4],r[5]), __fadd_rn(r[6],r[7])));
  }
  s2g[n] = __fadd_rn(blk[0], blk[1]);
  {
    unsigned int* dst = w_swz + (size_t)n * 128;
    #pragma unroll
    for (int qp = 0; qp < 32; ++qp){
      int sg = qp ^ (n & 7);
      f32x4 va = *(const f32x4*)(row + sg*8);
      f32x4 vb = *(const f32x4*)(row + sg*8 + 4);
      u32x4 pk = { pk2(va[0],va[1]), pk2(va[2],va[3]), pk2(vb[0],vb[1]), pk2(vb[2],vb[3]) };
      *(u32x4*)(dst + qp*4) = pk;
    }
  }
  #pragma unroll 4
  for (int c = 0; c < 256; ++c)
    wT[(size_t)c * 1024 + n] = row[c];
}

// ---------------- s1: np-pairwise f32 sum of z^2 per position (r7-proven, coalesced)
__global__ void vq_s1(const float* __restrict__ ze, float* __restrict__ s1g){
  int pos = blockIdx.x * 256 + threadIdx.x;
  int b = pos >> 12, hw = pos & 4095;
  const float* zp = ze + (size_t)b * CB * HWN + hw;
  float blk[2];
  #pragma unroll
  for (int b2 = 0; b2 < 2; ++b2){
    float r[8];
    for (int t = 0; t < 16; ++t)
      #pragma unroll
      for (int k = 0; k < 8; ++k){
        float x = zp[(size_t)(b2*128 + t*8 + k) * HWN];
        float q = __fmul_rn(x, x);
        if (t == 0) r[k] = q; else r[k] = __fadd_rn(r[k], q);
      }
    blk[b2] = __fadd_rn(__fadd_rn(__fadd_rn(r[0],r[1]), __fadd_rn(r[2],r[3])),
                        __fadd_rn(__fadd_rn(r[4],r[5]), __fadd_rn(r[6],r[7])));
  }
  s1g[pos] = __fadd_rn(blk[0], blk[1]);
}

// ---------------- screen loop: 4-slot ring, counted vmcnt(4), top-3 keys -> g_cand
__global__ __launch_bounds__(256, 2)
void vq_sloop(const float* __restrict__ ze, const unsigned int* __restrict__ w_swz,
              const float* __restrict__ s2g, const float* __restrict__ s1g,
              unsigned int* __restrict__ g_cand)
{
  __shared__ __align__(16) char smem[65536];   // 4 ring slots x 16KB; zeT overlays slots 2,3
  __shared__ float s2l[1024];
  __shared__ unsigned int m_key[64];
  __shared__ int   ovf[64];
  __shared__ unsigned int glist[GMAX];
  __shared__ int   ncand;

  const int tid = threadIdx.x, bid = blockIdx.x;
  const int b = bid >> 6, hw0 = (bid & 63) * 64;
  const int wid = tid >> 6, lane = tid & 63, l15 = lane & 15, lq = lane >> 4;
  const int wr = wid >> 1, wc = wid & 1;

  // issue B0 -> slot0, B1 -> slot1 (hide under phase A)
  {
    const char* wsrc = (const char*)w_swz;
    #pragma unroll
    for (int j = 0; j < 4; ++j){
      gld_lds16(wsrc + (j*256 + tid)*16,         smem +         (j*256 + wid*64)*16);
      gld_lds16(wsrc + 16384 + (j*256 + tid)*16, smem + 16384 + (j*256 + wid*64)*16);
    }
  }
  // phase A: raw f32 z -> bf16 zeT (RNE, granule-swizzled) into slots 2,3
  {
    const int p = tid & 63, cg = tid >> 6;
    const float* zp = ze + (size_t)b * CB * HWN + hw0 + p;
    #pragma unroll
    for (int o = 0; o < 8; ++o){
      int c0 = cg*64 + o*8;
      float v[8];
      #pragma unroll
      for (int i = 0; i < 8; ++i) v[i] = zp[(size_t)(c0 + i) * HWN];
      int g = (c0 >> 3) ^ (p & 7);
      u32x4 pk = { pk2(v[0],v[1]), pk2(v[2],v[3]), pk2(v[4],v[5]), pk2(v[6],v[7]) };
      *(u32x4*)(smem + 32768 + p*512 + g*16) = pk;
    }
    #pragma unroll
    for (int k = 0; k < 4; ++k) s2l[k*256 + tid] = s2g[k*256 + tid];
  }
  if (tid < 64){ m_key[tid] = 0xffffffffu; ovf[tid] = 0; }
  if (tid == 0) ncand = 0;
  asm volatile("s_waitcnt vmcnt(0)" ::: "memory");
  __syncthreads();

  float szr[8];
  {
    const float* s1b = s1g + (size_t)b * HWN + hw0;
    int rowbase = wr*32 + lq*4;
    #pragma unroll
    for (int m = 0; m < 2; ++m)
      #pragma unroll
      for (int r = 0; r < 4; ++r)
        szr[m*4+r] = s1b[rowbase + m*16 + r];
  }

  const int rA0 = wr*32 + l15, rA1 = rA0 + 16, rB = wc*16 + l15;

  // hoist A fragments from zeT (slots 2,3), then barrier before ring overwrites them
  short8 a0f[8], a1f[8];
  int boff[8];
  #pragma unroll
  for (int ks = 0; ks < 8; ++ks){
    int gk = ks*4 + lq;
    a0f[ks] = *(const short8*)(smem + 32768 + rA0*512 + ((gk ^ (rA0 & 7)) << 4));
    a1f[ks] = *(const short8*)(smem + 32768 + rA1*512 + ((gk ^ (rA1 & 7)) << 4));
    boff[ks] = rB*512 + ((gk ^ (rB & 7)) << 4);
  }
  __syncthreads();   // all hoists complete before slot2/3 prefetches land

  unsigned int k1[8], k2[8], k3[8];
  #pragma unroll
  for (int i = 0; i < 8; ++i){ k1[i] = k2[i] = k3[i] = 0xffffffffu; }

  for (int it = 0; it < 32; ++it){
    // prefetch it+2 into ring slot (it+2)&3; counted wait: keep prefetch in flight
    if (it < 30){
      const char* src = (const char*)w_swz + (size_t)(it + 2) * 16384;
      char* dst = smem + ((it + 2) & 3) * 16384;
      #pragma unroll
      for (int j = 0; j < 4; ++j)
        gld_lds16(src + (j*256 + tid)*16, dst + (j*256 + wid*64)*16);
      asm volatile("s_waitcnt vmcnt(4)" ::: "memory");
    } else if (it == 30){
      asm volatile("s_waitcnt vmcnt(4)" ::: "memory");
    } else {
      asm volatile("s_waitcnt vmcnt(0)" ::: "memory");
    }
    __syncthreads();   // single barrier per iteration (pre-compute)

    float sw = s2l[it*32 + wc*16 + l15];
    const int c0 = it*32 + wc*16 + l15;
    const char* Bc = smem + (it & 3) * 16384;

    f32x4 acc0 = {0,0,0,0}, acc1 = {0,0,0,0};
    #pragma unroll
    for (int ks = 0; ks < 8; ++ks){
      short8 b0 = *(const short8*)(Bc + boff[ks]);
      acc0 = __builtin_amdgcn_mfma_f32_16x16x32_bf16(a0f[ks], b0, acc0, 0, 0, 0);
      acc1 = __builtin_amdgcn_mfma_f32_16x16x32_bf16(a1f[ks], b0, acc1, 0, 0, 0);
    }

    #pragma unroll
    for (int m = 0; m < 2; ++m)
      #pragma unroll
      for (int r = 0; r < 4; ++r){
        int i = m*4 + r;
        float e = (m == 0) ? acc0[r] : acc1[r];
        float d = __fsub_rn(__fadd_rn(szr[i], sw), 2.0f*e);   // positive (chi2 norms)
        unsigned int key = (__float_as_uint(d) & KMASK) | (unsigned int)c0;
        if (key < k1[i]){ k3[i] = k2[i]; k2[i] = k1[i]; k1[i] = key; }
        else if (key < k2[i]){ k3[i] = k2[i]; k2[i] = key; }
        else if (key < k3[i]){ k3[i] = key; }
      }
  }

  // per-row min of keys
  #pragma unroll
  for (int i = 0; i < 8; ++i){
    unsigned int mk = k1[i];
    #pragma unroll
    for (int off = 1; off < 16; off <<= 1)
      mk = min(mk, (unsigned int)__shfl_xor((int)mk, off, 64));
    if (l15 == 0)
      atomicMin(&m_key[wr*32 + (i>>2)*16 + lq*4 + (i&3)], mk);
  }
  __syncthreads();

  // collect candidates; k3-in-window -> row overflow flag
  #pragma unroll
  for (int i = 0; i < 8; ++i){
    int row = wr*32 + (i>>2)*16 + lq*4 + (i&3);
    float tv = keyval(m_key[row]) + THRW;
    if (keyval(k1[i]) <= tv){
      int gi = atomicAdd(&ncand, 1);
      if (gi < GMAX) glist[gi] = ((unsigned int)row << 10) | (k1[i] & 1023u);
    }
    if (keyval(k2[i]) <= tv){
      int gi = atomicAdd(&ncand, 1);
      if (gi < GMAX) glist[gi] = ((unsigned int)row << 10) | (k2[i] & 1023u);
    }
    if (keyval(k3[i]) <= tv) ovf[row] = 1;
  }
  __syncthreads();

  // dump record: [0]=ncand_clamped, [1]=gov, entries[4..], ovf[4+GMAX..]
  unsigned int* rec = g_cand + (size_t)bid * RECU32;
  int nc = min(ncand, GMAX);
  if (tid == 0){ rec[0] = (unsigned int)nc; rec[1] = (ncand > GMAX) ? 1u : 0u; }
  if (tid < 64) rec[4 + GMAX + tid] = (unsigned int)ovf[tid];
  for (int ci = tid; ci < nc; ci += 256) rec[4 + ci] = glist[ci];
}

// ---------------- rerank: coalesced wave-per-candidate f64 + fallback -> selg
__global__ __launch_bounds__(256, 2)
void vq_rerank(const float* __restrict__ ze, const float* __restrict__ wcb,
               const float* __restrict__ wT, const float* __restrict__ s2g,
               const float* __restrict__ s1g, const unsigned int* __restrict__ g_cand,
               int* __restrict__ selg)
{
  __shared__ __align__(16) float zf[64*256];     // raw z, rotation-swizzled (64KB)
  __shared__ float s2l[1024];
  __shared__ float s1l[64];
  __shared__ float dex[GMAX];
  __shared__ unsigned int kd[64];
  __shared__ int   ki[64];
  __shared__ int   fbrow[64];
  __shared__ int   nfb;

  const int tid = threadIdx.x, bid = blockIdx.x;
  const int b = bid >> 6, hw0 = (bid & 63) * 64;
  const int wid = tid >> 6, lane = tid & 63;

  {
    const int p = tid & 63, cg = tid >> 6;
    const float* zp = ze + (size_t)b * CB * HWN + hw0 + p;
    #pragma unroll 8
    for (int k = 0; k < 64; ++k){
      int c = cg*64 + k;
      zf[p*256 + ((c + p) & 255)] = zp[(size_t)c * HWN];
    }
    #pragma unroll
    for (int k = 0; k < 4; ++k) s2l[k*256 + tid] = s2g[k*256 + tid];
  }
  if (tid < 64){ kd[tid] = 0xffffffffu; ki[tid] = 0x7fffffff;
                 s1l[tid] = s1g[(size_t)b * HWN + hw0 + tid]; }
  if (tid == 0) nfb = 0;
  __syncthreads();

  const unsigned int* rec = g_cand + (size_t)bid * RECU32;
  const int nc  = (int)rec[0];
  const int gov = (int)rec[1];

  for (int ci = wid; ci < nc; ci += 4){
    unsigned int ent = rec[4 + ci];
    int pos = (int)(ent >> 10), code = (int)(ent & 1023u);
    const float* wrow = wcb + (size_t)code * CB;
    double a = 0.0;
    #pragma unroll
    for (int k = 0; k < 4; ++k){
      int c = k*64 + lane;
      a = fma((double)zf[pos*256 + ((c + pos) & 255)], (double)wrow[c], a);
    }
    #pragma unroll
    for (int off = 1; off < 64; off <<= 1)
      a += __shfl_xor(a, off, 64);
    float e32 = (float)a;
    float d = __fsub_rn(__fadd_rn(s1l[pos], s2l[code]), __fmul_rn(2.0f, e32));
    if (lane == 0){
      dex[ci] = d;
      atomicMin(&kd[pos], __float_as_uint(d));
    }
  }
  __syncthreads();
  for (int ci = tid; ci < nc; ci += 256){
    unsigned int ent = rec[4 + ci];
    int pos = (int)(ent >> 10), code = (int)(ent & 1023u);
    if (__float_as_uint(dex[ci]) == kd[pos]) atomicMin(&ki[pos], code);
  }
  __syncthreads();

  if (tid < 64){
    if (rec[4 + GMAX + tid] || gov){
      int s = atomicAdd(&nfb, 1);
      fbrow[s] = tid;
      kd[tid] = 0xffffffffu; ki[tid] = 0x7fffffff;
    }
  }
  __syncthreads();
  #pragma unroll 1
  for (int f = 0; f < nfb; ++f){
    const int row = fbrow[f];
    const float s1p = s1l[row];
    double a0 = 0.0, a1 = 0.0, a2 = 0.0, a3 = 0.0;
    #pragma unroll 1
    for (int c = 0; c < 256; ++c){
      double zc = (double)zf[row*256 + ((c + row) & 255)];
      const float* wc4 = wT + (size_t)c * 1024 + tid;
      a0 = fma(zc, (double)wc4[0],   a0);
      a1 = fma(zc, (double)wc4[256], a1);
      a2 = fma(zc, (double)wc4[512], a2);
      a3 = fma(zc, (double)wc4[768], a3);
    }
    float dv[4];
    dv[0] = __fsub_rn(__fadd_rn(s1p, s2l[tid      ]), __fmul_rn(2.0f, (float)a0));
    dv[1] = __fsub_rn(__fadd_rn(s1p, s2l[tid + 256]), __fmul_rn(2.0f, (float)a1));
    dv[2] = __fsub_rn(__fadd_rn(s1p, s2l[tid + 512]), __fmul_rn(2.0f, (float)a2));
    dv[3] = __fsub_rn(__fadd_rn(s1p, s2l[tid + 768]), __fmul_rn(2.0f, (float)a3));
    #pragma unroll
    for (int j = 0; j < 4; ++j) atomicMin(&kd[row], __float_as_uint(dv[j]));
    __syncthreads();
    unsigned int kmin = kd[row];
    #pragma unroll
    for (int j = 0; j < 4; ++j)
      if (__float_as_uint(dv[j]) == kmin) atomicMin(&ki[row], tid + j*256);
    __syncthreads();
  }

  if (tid < 64) selg[(size_t)b * HWN + hw0 + tid] = ki[tid];
}

// ---------------- epilogue: streaming STE + loss; gathers via L1-resident wT row
__global__ __launch_bounds__(256)
void vq_epi(const float* __restrict__ ze, const float* __restrict__ wT,
            const int* __restrict__ selg, float* __restrict__ out,
            float* __restrict__ partial)
{
  __shared__ float red[256];
  const int tid = threadIdx.x, bid = blockIdx.x;
  const int b = bid >> 8, c = bid & 255;
  const float* zrow = ze  + ((size_t)b * CB + c) * HWN;
  float*       orow = out + ((size_t)b * CB + c) * HWN;
  const int*   srow = selg + (size_t)b * HWN;
  const float* wrow = wT + (size_t)c * 1024;
  float lacc = 0.f;
  #pragma unroll
  for (int k = 0; k < 4; ++k){
    int base = (k*256 + tid) * 4;
    f32x4 z4 = *(const f32x4*)(zrow + base);
    i32x4 s4 = *(const i32x4*)(srow + base);
    f32x4 o4;
    #pragma unroll
    for (int e = 0; e < 4; ++e){
      float zq = wrow[s4[e]];
      float zfv = z4[e];
      float st = __fadd_rn(zfv, __fsub_rn(zq, zfv));   // f32 STE
      o4[e] = rbf(st);                                 // final bf16 cast
      float dd = __fsub_rn(zfv, zq);
      lacc = __fadd_rn(lacc, __fmul_rn(dd, dd));
    }
    *(f32x4*)(orow + base) = o4;
  }
  red[tid] = lacc;
  __syncthreads();
  for (int s = 128; s > 0; s >>= 1){
    if (tid < s) red[tid] += red[tid + s];
    __syncthreads();
  }
  if (tid == 0) partial[bid] = red[0];
}

// ---------------- loss
__global__ void vq_loss(const float* __restrict__ partial, float* __restrict__ outl){
  int t = threadIdx.x;
  if (t < 16){
    float s = 0.f;
    for (int j = 0; j < 256; ++j) s += partial[t*256 + j];
    float m = __fmul_rn(s, 1.0f / 1048576.0f);
    outl[t] = rbf(__fadd_rn(m, __fmul_rn(0.25f, m)));
  }
}

extern "C" void kernel_launch(void* const* d_in, const int* in_sizes, int n_in,
                              void* d_out, int out_size, void* d_ws, size_t ws_size,
                              hipStream_t stream)
{
  const float* ze  = (const float*)d_in[0];   // z_e  [16,256,64,64] raw f32
  const float* wcb = (const float*)d_in[1];   // embed_w [1024,256] raw f32
  float* out = (float*)d_out;                 // z_q_st (bf16-grid f32) + vq_loss[16]
  float* s2g     = (float*)d_ws;              // [1024]
  float* s1g     = s2g + 1024;                // [65536]
  int*   selg    = (int*)(s1g + 65536);       // [65536]
  float* partial = (float*)(selg + 65536);    // [4096]
  unsigned int* w_swz  = (unsigned int*)(partial + 4096);  // [131072] u32 = 512 KB
  float* wT            = (float*)(w_swz + 131072);         // [262144] f32 = 1 MB
  unsigned int* g_cand = (unsigned int*)(wT + 262144);     // [1024*RECU32] = 1.6 MB

  hipLaunchKernelGGL(vq_prep,   dim3(4),    dim3(256), 0, stream, wcb, s2g, w_swz, wT);
  hipLaunchKernelGGL(vq_s1,     dim3(256),  dim3(256), 0, stream, ze, s1g);
  hipLaunchKernelGGL(vq_sloop,  dim3(1024), dim3(256), 0, stream,
                     ze, w_swz, s2g, s1g, g_cand);
  hipLaunchKernelGGL(vq_rerank, dim3(1024), dim3(256), 0, stream,
                     ze, wcb, wT, s2g, s1g, g_cand, selg);
  hipLaunchKernelGGL(vq_epi,    dim3(4096), dim3(256), 0, stream,
                     ze, wT, selg, out, partial);
  hipLaunchKernelGGL(vq_loss,   dim3(1),    dim3(64), 0, stream,
                     partial, out + (size_t)16 * 256 * 4096);
}

// Round 16
// 330.439 us; speedup vs baseline: 1.4002x; 1.2559x over previous
//
#include <hip/hip_runtime.h>
#include <stdint.h>

typedef __attribute__((ext_vector_type(8))) short short8;
typedef __attribute__((ext_vector_type(4))) float f32x4;
typedef __attribute__((ext_vector_type(4))) int   i32x4;
typedef __attribute__((ext_vector_type(4))) unsigned int u32x4;

#define CB 256
#define HWN 4096
#define THRW 0.75f           // window: MFMA-vs-np bound (~0.46) + 2*key-trunc (0.0625) + margin
#define KMASK 0xFFFFFC00u    // strip 10 low mantissa bits (code field)
#define GMAX 320             // block-wide candidate list capacity
#define RECU32 400           // per-block record stride (u32): 4 hdr + 320 entries + 64 ovf

// RNE fp32 -> bf16-grid fp32 (final output cast)
static __device__ __forceinline__ float rbf(float x){
  unsigned int u = __builtin_bit_cast(unsigned int, x);
  u = (u + 0x7fffu + ((u >> 16) & 1u)) & 0xffff0000u;
  return __builtin_bit_cast(float, u);
}
static __device__ __forceinline__ unsigned int pk2(float a, float b){
  unsigned int ua = __builtin_bit_cast(unsigned int, a);
  unsigned int ub = __builtin_bit_cast(unsigned int, b);
  ua = (ua + 0x7fffu + ((ua >> 16) & 1u)) >> 16;
  ub = (ub + 0x7fffu + ((ub >> 16) & 1u)) & 0xffff0000u;
  return ua | ub;
}
static __device__ __forceinline__ void gld_lds16(const void* g, void* l){
  __builtin_amdgcn_global_load_lds(
      (const __attribute__((address_space(1))) unsigned int*)g,
      (__attribute__((address_space(3))) unsigned int*)l, 16, 0, 0);
}
static __device__ __forceinline__ float keyval(unsigned int k){
  return __builtin_bit_cast(float, k & KMASK);
}

// ---------------- prep: s2[n] (np-pairwise, r7-proven) + swizzled bf16 image + wT
__global__ void vq_prep(const float* __restrict__ wcb, float* __restrict__ s2g,
                        unsigned int* __restrict__ w_swz, float* __restrict__ wT){
  int n = blockIdx.x * 256 + threadIdx.x;
  const float* row = wcb + (size_t)n * CB;
  float blk[2];
  #pragma unroll
  for (int b2 = 0; b2 < 2; ++b2){
    float r[8];
    #pragma unroll
    for (int k = 0; k < 8; ++k){ float x = row[b2*128 + k]; r[k] = __fmul_rn(x, x); }
    for (int t = 1; t < 16; ++t)
      #pragma unroll
      for (int k = 0; k < 8; ++k){
        float x = row[b2*128 + t*8 + k];
        r[k] = __fadd_rn(r[k], __fmul_rn(x, x));
      }
    blk[b2] = __fadd_rn(__fadd_rn(__fadd_rn(r[0],r[1]), __fadd_rn(r[2],r[3])),
                        __fadd_rn(__fadd_rn(r[4],r[5]), __fadd_rn(r[6],r[7])));
  }
  s2g[n] = __fadd_rn(blk[0], blk[1]);
  {
    unsigned int* dst = w_swz + (size_t)n * 128;
    #pragma unroll
    for (int qp = 0; qp < 32; ++qp){
      int sg = qp ^ (n & 7);
      f32x4 va = *(const f32x4*)(row + sg*8);
      f32x4 vb = *(const f32x4*)(row + sg*8 + 4);
      u32x4 pk = { pk2(va[0],va[1]), pk2(va[2],va[3]), pk2(vb[0],vb[1]), pk2(vb[2],vb[3]) };
      *(u32x4*)(dst + qp*4) = pk;
    }
  }
  #pragma unroll 4
  for (int c = 0; c < 256; ++c)
    wT[(size_t)c * 1024 + n] = row[c];
}

// ---------------- s1: np-pairwise f32 sum of z^2 per position (r7-proven, coalesced)
__global__ void vq_s1(const float* __restrict__ ze, float* __restrict__ s1g){
  int pos = blockIdx.x * 256 + threadIdx.x;
  int b = pos >> 12, hw = pos & 4095;
  const float* zp = ze + (size_t)b * CB * HWN + hw;
  float blk[2];
  #pragma unroll
  for (int b2 = 0; b2 < 2; ++b2){
    float r[8];
    for (int t = 0; t < 16; ++t)
      #pragma unroll
      for (int k = 0; k < 8; ++k){
        float x = zp[(size_t)(b2*128 + t*8 + k) * HWN];
        float q = __fmul_rn(x, x);
        if (t == 0) r[k] = q; else r[k] = __fadd_rn(r[k], q);
      }
    blk[b2] = __fadd_rn(__fadd_rn(__fadd_rn(r[0],r[1]), __fadd_rn(r[2],r[3])),
                        __fadd_rn(__fadd_rn(r[4],r[5]), __fadd_rn(r[6],r[7])));
  }
  s1g[pos] = __fadd_rn(blk[0], blk[1]);
}

// ---------------- screen loop: 2-slot ring (T3 minimum recipe), 4 blocks/CU,
//                  branchless top-3 keys -> g_cand
__global__ __launch_bounds__(256, 4)
void vq_sloop(const float* __restrict__ ze, const unsigned int* __restrict__ w_swz,
              const float* __restrict__ s2g, const float* __restrict__ s1g,
              unsigned int* __restrict__ g_cand)
{
  __shared__ __align__(16) char smem[32768];   // zeT (phase A) -> 2 ring slots x 16KB
  __shared__ float s2l[1024];
  __shared__ unsigned int m_key[64];
  __shared__ int   ovf[64];
  __shared__ unsigned int glist[GMAX];
  __shared__ int   ncand;

  const int tid = threadIdx.x, bid = blockIdx.x;
  const int b = bid >> 6, hw0 = (bid & 63) * 64;
  const int wid = tid >> 6, lane = tid & 63, l15 = lane & 15, lq = lane >> 4;
  const int wr = wid >> 1, wc = wid & 1;

  // phase A: raw f32 z -> bf16 zeT (RNE, granule-swizzled) into [0,32K); s2 -> LDS
  {
    const int p = tid & 63, cg = tid >> 6;
    const float* zp = ze + (size_t)b * CB * HWN + hw0 + p;
    #pragma unroll
    for (int o = 0; o < 8; ++o){
      int c0 = cg*64 + o*8;
      float v[8];
      #pragma unroll
      for (int i = 0; i < 8; ++i) v[i] = zp[(size_t)(c0 + i) * HWN];
      int g = (c0 >> 3) ^ (p & 7);
      u32x4 pk = { pk2(v[0],v[1]), pk2(v[2],v[3]), pk2(v[4],v[5]), pk2(v[6],v[7]) };
      *(u32x4*)(smem + p*512 + g*16) = pk;
    }
    #pragma unroll
    for (int k = 0; k < 4; ++k) s2l[k*256 + tid] = s2g[k*256 + tid];
  }
  if (tid < 64){ m_key[tid] = 0xffffffffu; ovf[tid] = 0; }
  if (tid == 0) ncand = 0;
  __syncthreads();

  float szr[8];
  {
    const float* s1b = s1g + (size_t)b * HWN + hw0;
    int rowbase = wr*32 + lq*4;
    #pragma unroll
    for (int m = 0; m < 2; ++m)
      #pragma unroll
      for (int r = 0; r < 4; ++r)
        szr[m*4+r] = s1b[rowbase + m*16 + r];
  }

  const int rA0 = wr*32 + l15, rA1 = rA0 + 16, rB = wc*16 + l15;

  // hoist A fragments from zeT; after barrier the region becomes the B ring
  short8 a0f[8], a1f[8];
  int boff[8];
  #pragma unroll
  for (int ks = 0; ks < 8; ++ks){
    int gk = ks*4 + lq;
    a0f[ks] = *(const short8*)(smem + rA0*512 + ((gk ^ (rA0 & 7)) << 4));
    a1f[ks] = *(const short8*)(smem + rA1*512 + ((gk ^ (rA1 & 7)) << 4));
    boff[ks] = rB*512 + ((gk ^ (rB & 7)) << 4);
  }
  __syncthreads();   // all hoists done; zeT region free for ring

  unsigned int k1[8], k2[8], k3[8];
  #pragma unroll
  for (int i = 0; i < 8; ++i){ k1[i] = k2[i] = k3[i] = 0xffffffffu; }

  // prologue: stage B0 -> slot0
  {
    const char* src = (const char*)w_swz;
    #pragma unroll
    for (int j = 0; j < 4; ++j)
      gld_lds16(src + (j*256 + tid)*16, smem + (j*256 + wid*64)*16);
  }
  asm volatile("s_waitcnt vmcnt(0)" ::: "memory");
  __syncthreads();

  int cur = 0;
  #pragma unroll 1
  for (int it = 0; it < 32; ++it){
    if (it < 31){   // stage it+1 into other slot (barrier of it-1 protects readers)
      const char* src = (const char*)w_swz + (size_t)(it + 1) * 16384;
      char* dst = smem + (cur^1)*16384;
      #pragma unroll
      for (int j = 0; j < 4; ++j)
        gld_lds16(src + (j*256 + tid)*16, dst + (j*256 + wid*64)*16);
    }
    float sw = s2l[it*32 + wc*16 + l15];
    const unsigned int c0 = (unsigned int)(it*32 + wc*16 + l15);
    const char* Bc = smem + cur*16384;

    f32x4 acc0 = {0,0,0,0}, acc1 = {0,0,0,0};
    #pragma unroll
    for (int ks = 0; ks < 8; ++ks){
      short8 b0 = *(const short8*)(Bc + boff[ks]);
      acc0 = __builtin_amdgcn_mfma_f32_16x16x32_bf16(a0f[ks], b0, acc0, 0, 0, 0);
      acc1 = __builtin_amdgcn_mfma_f32_16x16x32_bf16(a1f[ks], b0, acc1, 0, 0, 0);
    }

    // dist -> key -> branchless top-3 (min/max lattice, 5 ops)
    #pragma unroll
    for (int m = 0; m < 2; ++m)
      #pragma unroll
      for (int r = 0; r < 4; ++r){
        int i = m*4 + r;
        float e = (m == 0) ? acc0[r] : acc1[r];
        float d = __fsub_rn(__fadd_rn(szr[i], sw), 2.0f*e);   // positive (chi2 norms)
        unsigned int key = (__float_as_uint(d) & KMASK) | c0;
        unsigned int mx1 = max(k1[i], key); k1[i] = min(k1[i], key);
        unsigned int mx2 = max(k2[i], mx1); k2[i] = min(k2[i], mx1);
        k3[i] = min(k3[i], mx2);
      }

    asm volatile("s_waitcnt vmcnt(0)" ::: "memory");
    __syncthreads();
    cur ^= 1;
  }

  // per-row min of keys
  #pragma unroll
  for (int i = 0; i < 8; ++i){
    unsigned int mk = k1[i];
    #pragma unroll
    for (int off = 1; off < 16; off <<= 1)
      mk = min(mk, (unsigned int)__shfl_xor((int)mk, off, 64));
    if (l15 == 0)
      atomicMin(&m_key[wr*32 + (i>>2)*16 + lq*4 + (i&3)], mk);
  }
  __syncthreads();

  // collect candidates; k3-in-window -> row overflow flag
  #pragma unroll
  for (int i = 0; i < 8; ++i){
    int row = wr*32 + (i>>2)*16 + lq*4 + (i&3);
    float tv = keyval(m_key[row]) + THRW;
    if (keyval(k1[i]) <= tv){
      int gi = atomicAdd(&ncand, 1);
      if (gi < GMAX) glist[gi] = ((unsigned int)row << 10) | (k1[i] & 1023u);
    }
    if (keyval(k2[i]) <= tv){
      int gi = atomicAdd(&ncand, 1);
      if (gi < GMAX) glist[gi] = ((unsigned int)row << 10) | (k2[i] & 1023u);
    }
    if (keyval(k3[i]) <= tv) ovf[row] = 1;
  }
  __syncthreads();

  // dump record: [0]=ncand_clamped, [1]=gov, entries[4..], ovf[4+GMAX..]
  unsigned int* rec = g_cand + (size_t)bid * RECU32;
  int nc = min(ncand, GMAX);
  if (tid == 0){ rec[0] = (unsigned int)nc; rec[1] = (ncand > GMAX) ? 1u : 0u; }
  if (tid < 64) rec[4 + GMAX + tid] = (unsigned int)ovf[tid];
  for (int ci = tid; ci < nc; ci += 256) rec[4 + ci] = glist[ci];
}

// ---------------- rerank: 16-lane-group-per-candidate f64 + fallback -> selg
__global__ __launch_bounds__(256, 2)
void vq_rerank(const float* __restrict__ ze, const float* __restrict__ wcb,
               const float* __restrict__ wT, const float* __restrict__ s2g,
               const float* __restrict__ s1g, const unsigned int* __restrict__ g_cand,
               int* __restrict__ selg)
{
  __shared__ __align__(16) float zf[64*256];     // raw z, rotation-swizzled (64KB)
  __shared__ float s2l[1024];
  __shared__ float s1l[64];
  __shared__ float dex[GMAX];
  __shared__ unsigned int kd[64];
  __shared__ int   ki[64];
  __shared__ int   fbrow[64];
  __shared__ int   nfb;

  const int tid = threadIdx.x, bid = blockIdx.x;
  const int b = bid >> 6, hw0 = (bid & 63) * 64;
  const int wid = tid >> 6, lane = tid & 63;
  const int grp = lane >> 4, gl = lane & 15;

  {
    const int p = tid & 63, cg = tid >> 6;
    const float* zp = ze + (size_t)b * CB * HWN + hw0 + p;
    #pragma unroll 8
    for (int k = 0; k < 64; ++k){
      int c = cg*64 + k;
      zf[p*256 + ((c + p) & 255)] = zp[(size_t)c * HWN];
    }
    #pragma unroll
    for (int k = 0; k < 4; ++k) s2l[k*256 + tid] = s2g[k*256 + tid];
  }
  if (tid < 64){ kd[tid] = 0xffffffffu; ki[tid] = 0x7fffffff;
                 s1l[tid] = s1g[(size_t)b * HWN + hw0 + tid]; }
  if (tid == 0) nfb = 0;
  __syncthreads();

  const unsigned int* rec = g_cand + (size_t)bid * RECU32;
  const int nc  = (int)rec[0];
  const int gov = (int)rec[1];

  // one candidate per 16-lane group: 4 concurrent per wave, 4-step tree
  for (int cb = wid*4; cb < nc; cb += 16){
    const int ci = cb + grp;
    const bool act = ci < nc;
    double a = 0.0;
    int pos = 0, code = 0;
    if (act){
      unsigned int ent = rec[4 + ci];
      pos = (int)(ent >> 10); code = (int)(ent & 1023u);
      const float* wrow = wcb + (size_t)code * CB;
      double a0 = 0.0, a1 = 0.0;
      #pragma unroll
      for (int k = 0; k < 16; k += 2){
        int ca = k*16 + gl, cbn = (k+1)*16 + gl;
        a0 = fma((double)zf[pos*256 + ((ca  + pos) & 255)], (double)wrow[ca],  a0);
        a1 = fma((double)zf[pos*256 + ((cbn + pos) & 255)], (double)wrow[cbn], a1);
      }
      a = a0 + a1;
    }
    #pragma unroll
    for (int off = 1; off < 16; off <<= 1)
      a += __shfl_xor(a, off, 64);          // stays within the 16-lane group
    if (act && gl == 0){
      float e32 = (float)a;
      float d = __fsub_rn(__fadd_rn(s1l[pos], s2l[code]), __fmul_rn(2.0f, e32));
      dex[ci] = d;
      atomicMin(&kd[pos], __float_as_uint(d));
    }
  }
  __syncthreads();
  for (int ci = tid; ci < nc; ci += 256){
    unsigned int ent = rec[4 + ci];
    int pos = (int)(ent >> 10), code = (int)(ent & 1023u);
    if (__float_as_uint(dex[ci]) == kd[pos]) atomicMin(&ki[pos], code);
  }
  __syncthreads();

  if (tid < 64){
    if (rec[4 + GMAX + tid] || gov){
      int s = atomicAdd(&nfb, 1);
      fbrow[s] = tid;
      kd[tid] = 0xffffffffu; ki[tid] = 0x7fffffff;
    }
  }
  __syncthreads();
  #pragma unroll 1
  for (int f = 0; f < nfb; ++f){
    const int row = fbrow[f];
    const float s1p = s1l[row];
    double a0 = 0.0, a1 = 0.0, a2 = 0.0, a3 = 0.0;
    #pragma unroll 1
    for (int c = 0; c < 256; ++c){
      double zc = (double)zf[row*256 + ((c + row) & 255)];
      const float* wc4 = wT + (size_t)c * 1024 + tid;
      a0 = fma(zc, (double)wc4[0],   a0);
      a1 = fma(zc, (double)wc4[256], a1);
      a2 = fma(zc, (double)wc4[512], a2);
      a3 = fma(zc, (double)wc4[768], a3);
    }
    float dv[4];
    dv[0] = __fsub_rn(__fadd_rn(s1p, s2l[tid      ]), __fmul_rn(2.0f, (float)a0));
    dv[1] = __fsub_rn(__fadd_rn(s1p, s2l[tid + 256]), __fmul_rn(2.0f, (float)a1));
    dv[2] = __fsub_rn(__fadd_rn(s1p, s2l[tid + 512]), __fmul_rn(2.0f, (float)a2));
    dv[3] = __fsub_rn(__fadd_rn(s1p, s2l[tid + 768]), __fmul_rn(2.0f, (float)a3));
    #pragma unroll
    for (int j = 0; j < 4; ++j) atomicMin(&kd[row], __float_as_uint(dv[j]));
    __syncthreads();
    unsigned int kmin = kd[row];
    #pragma unroll
    for (int j = 0; j < 4; ++j)
      if (__float_as_uint(dv[j]) == kmin) atomicMin(&ki[row], tid + j*256);
    __syncthreads();
  }

  if (tid < 64) selg[(size_t)b * HWN + hw0 + tid] = ki[tid];
}

// ---------------- epilogue: streaming STE + loss; gathers via L1-resident wT row
__global__ __launch_bounds__(256)
void vq_epi(const float* __restrict__ ze, const float* __restrict__ wT,
            const int* __restrict__ selg, float* __restrict__ out,
            float* __restrict__ partial)
{
  __shared__ float red[256];
  const int tid = threadIdx.x, bid = blockIdx.x;
  const int b = bid >> 8, c = bid & 255;
  const float* zrow = ze  + ((size_t)b * CB + c) * HWN;
  float*       orow = out + ((size_t)b * CB + c) * HWN;
  const int*   srow = selg + (size_t)b * HWN;
  const float* wrow = wT + (size_t)c * 1024;
  float lacc = 0.f;
  #pragma unroll
  for (int k = 0; k < 4; ++k){
    int base = (k*256 + tid) * 4;
    f32x4 z4 = *(const f32x4*)(zrow + base);
    i32x4 s4 = *(const i32x4*)(srow + base);
    f32x4 o4;
    #pragma unroll
    for (int e = 0; e < 4; ++e){
      float zq = wrow[s4[e]];
      float zfv = z4[e];
      float st = __fadd_rn(zfv, __fsub_rn(zq, zfv));   // f32 STE
      o4[e] = rbf(st);                                 // final bf16 cast
      float dd = __fsub_rn(zfv, zq);
      lacc = __fadd_rn(lacc, __fmul_rn(dd, dd));
    }
    *(f32x4*)(orow + base) = o4;
  }
  red[tid] = lacc;
  __syncthreads();
  for (int s = 128; s > 0; s >>= 1){
    if (tid < s) red[tid] += red[tid + s];
    __syncthreads();
  }
  if (tid == 0) partial[bid] = red[0];
}

// ---------------- loss
__global__ void vq_loss(const float* __restrict__ partial, float* __restrict__ outl){
  int t = threadIdx.x;
  if (t < 16){
    float s = 0.f;
    for (int j = 0; j < 256; ++j) s += partial[t*256 + j];
    float m = __fmul_rn(s, 1.0f / 1048576.0f);
    outl[t] = rbf(__fadd_rn(m, __fmul_rn(0.25f, m)));
  }
}

extern "C" void kernel_launch(void* const* d_in, const int* in_sizes, int n_in,
                              void* d_out, int out_size, void* d_ws, size_t ws_size,
                              hipStream_t stream)
{
  const float* ze  = (const float*)d_in[0];   // z_e  [16,256,64,64] raw f32
  const float* wcb = (const float*)d_in[1];   // embed_w [1024,256] raw f32
  float* out = (float*)d_out;                 // z_q_st (bf16-grid f32) + vq_loss[16]
  float* s2g     = (float*)d_ws;              // [1024]
  float* s1g     = s2g + 1024;                // [65536]
  int*   selg    = (int*)(s1g + 65536);       // [65536]
  float* partial = (float*)(selg + 65536);    // [4096]
  unsigned int* w_swz  = (unsigned int*)(partial + 4096);  // [131072] u32 = 512 KB
  float* wT            = (float*)(w_swz + 131072);         // [262144] f32 = 1 MB
  unsigned int* g_cand = (unsigned int*)(wT + 262144);     // [1024*RECU32] = 1.6 MB

  hipLaunchKernelGGL(vq_prep,   dim3(4),    dim3(256), 0, stream, wcb, s2g, w_swz, wT);
  hipLaunchKernelGGL(vq_s1,     dim3(256),  dim3(256), 0, stream, ze, s1g);
  hipLaunchKernelGGL(vq_sloop,  dim3(1024), dim3(256), 0, stream,
                     ze, w_swz, s2g, s1g, g_cand);
  hipLaunchKernelGGL(vq_rerank, dim3(1024), dim3(256), 0, stream,
                     ze, wcb, wT, s2g, s1g, g_cand, selg);
  hipLaunchKernelGGL(vq_epi,    dim3(4096), dim3(256), 0, stream,
                     ze, wT, selg, out, partial);
  hipLaunchKernelGGL(vq_loss,   dim3(1),    dim3(64), 0, stream,
                     partial, out + (size_t)16 * 256 * 4096);
}